// Round 1
// baseline (5123.957 us; speedup 1.0000x reference)
//
#include <hip/hip_runtime.h>
#include <cstddef>

// Problem constants
#define B_TOT 4096
#define T_LEN 168
#define D_IN  16
#define H_DIM 96
#define G_DIM 384   // 4*H

// Kernel config
#define BB    16                 // batch rows per block -> 256 blocks = 1/CU
#define NTHR  768                // 12 waves = 3/SIMD (balanced)
#define SMEM_BYTES ((G_DIM*H_DIM + BB*H_DIM) * 4)   // 147456 + 6144 = 153600 B

// ws layout: h1 (B,T,H) fp32 = 252 MiB (assumed <= ws_size)
#define H1_ELEMS ((size_t)B_TOT * T_LEN * H_DIM)

__device__ __forceinline__ float sigm(float x) {
  return __fdividef(1.f, 1.f + __expf(-x));
}
__device__ __forceinline__ float tanh_fast(float x) {
  // tanh via exp(-2|x|): overflow-safe, then restore sign
  float ax = fabsf(x);
  float z  = __expf(-2.f * ax);
  float t  = __fdividef(1.f - z, 1.f + z);
  return copysignf(t, x);
}

// One LSTM layer, persistent over all T steps.
// Thread map: tid = (bq*96 + u)*4 + kq
//   u  = hidden unit (0..95), bq = batch-octet (0..1), kq = k-quarter (0..3)
// Each thread: partial dots (4 gate types x 8 batches x 24 k) -> shfl-combine
// over kq -> full i/f/g/o update for 2 (b,u) pairs; c lives in registers.
template<int K_IN, bool WRITE_H, bool LAST_FC>
__global__ __launch_bounds__(NTHR)
void lstm_kernel(const float* __restrict__ in,     // (B,T,K_IN)
                 const float* __restrict__ wih,    // (384,K_IN) row-major
                 const float* __restrict__ whh,    // (384,96) row-major
                 const float* __restrict__ bih,    // (384)
                 const float* __restrict__ bhh,    // (384)
                 float* __restrict__ h_out,        // (B,T,96) or unused
                 const float* __restrict__ wfc,    // (96) or unused
                 const float* __restrict__ bfc,    // (1) or unused
                 float* __restrict__ out)          // (B,) or unused
{
  extern __shared__ float smem[];
  float* whh_s = smem;                 // 36864 floats, chunk-rotated
  float* h_s   = smem + G_DIM*H_DIM;   // 1536 floats = h tile [16][96]

  const int tid = threadIdx.x;
  const int b0  = blockIdx.x * BB;

  // Stage Whh into LDS with chunk rotation: element chunk (g, c) stored at
  // g*24 + (c+g)%24.  Rotation makes every ds_read_b128 phase-group hit
  // distinct banks (96 floats/row = 384 B = bank-period; (c+g)%24 -> +4*(..mod 8)).
  {
    const float4* src = (const float4*)whh;
    float4* dst = (float4*)whh_s;
    for (int idx = tid; idx < G_DIM*24; idx += NTHR) {
      int g = idx / 24;
      int c = idx - g*24;
      int cr = (c + g) % 24;
      dst[g*24 + cr] = src[idx];
    }
  }
  for (int idx = tid; idx < BB*H_DIM; idx += NTHR) h_s[idx] = 0.f;  // h0 = 0

  const int kq = tid & 3;
  const int p  = tid >> 2;      // 0..191
  const int u  = p % 96;
  const int bq = p / 96;        // 0..1  (8 batches each)

  float bias[4];
  #pragma unroll
  for (int j = 0; j < 4; ++j) bias[j] = bih[u + 96*j] + bhh[u + 96*j];

  float cst0 = 0.f, cst1 = 0.f;   // c-state for this thread's 2 (b,u) pairs

  constexpr int ACH = K_IN / 16;          // A-part chunks per k-quarter (1 or 6)
  const int r0    = (u + kq*6) % 24;      // rotation base for B-part reads
  const int wbase = u * 96;

  const float* wih_r0 = wih + (size_t)(u      ) * K_IN;
  const float* wih_r1 = wih + (size_t)(u +  96) * K_IN;
  const float* wih_r2 = wih + (size_t)(u + 192) * K_IN;
  const float* wih_r3 = wih + (size_t)(u + 288) * K_IN;

  __syncthreads();

  for (int t = 0; t < T_LEN; ++t) {
    float acc[4][8];
    #pragma unroll
    for (int j = 0; j < 4; ++j)
      #pragma unroll
      for (int i = 0; i < 8; ++i) acc[j][i] = 0.f;

    // ---- A-part: input projection (weights from global; L1/L2-hot) ----
    #pragma unroll
    for (int ca = 0; ca < ACH; ++ca) {
      const int c = kq*ACH + ca;
      const float4 w0 = *(const float4*)(wih_r0 + 4*c);
      const float4 w1 = *(const float4*)(wih_r1 + 4*c);
      const float4 w2 = *(const float4*)(wih_r2 + 4*c);
      const float4 w3 = *(const float4*)(wih_r3 + 4*c);
      #pragma unroll
      for (int i = 0; i < 8; ++i) {
        const int b = bq*8 + i;
        const float4 xv = *(const float4*)(in + ((size_t)(b0+b)*T_LEN + t)*K_IN + 4*c);
        acc[0][i] = fmaf(w0.x,xv.x,fmaf(w0.y,xv.y,fmaf(w0.z,xv.z,fmaf(w0.w,xv.w,acc[0][i]))));
        acc[1][i] = fmaf(w1.x,xv.x,fmaf(w1.y,xv.y,fmaf(w1.z,xv.z,fmaf(w1.w,xv.w,acc[1][i]))));
        acc[2][i] = fmaf(w2.x,xv.x,fmaf(w2.y,xv.y,fmaf(w2.z,xv.z,fmaf(w2.w,xv.w,acc[2][i]))));
        acc[3][i] = fmaf(w3.x,xv.x,fmaf(w3.y,xv.y,fmaf(w3.z,xv.z,fmaf(w3.w,xv.w,acc[3][i]))));
      }
    }

    // ---- B-part: recurrent h @ Whh^T (weights from swizzled LDS) ----
    #pragma unroll
    for (int cb = 0; cb < 6; ++cb) {
      const int c = kq*6 + cb;
      int cr = r0 + cb; if (cr >= 24) cr -= 24;
      const float4 w0 = *(const float4*)&whh_s[wbase         + 4*cr];
      const float4 w1 = *(const float4*)&whh_s[wbase +  9216 + 4*cr];
      const float4 w2 = *(const float4*)&whh_s[wbase + 18432 + 4*cr];
      const float4 w3 = *(const float4*)&whh_s[wbase + 27648 + 4*cr];
      #pragma unroll
      for (int i = 0; i < 8; ++i) {
        const float4 hv = *(const float4*)&h_s[(bq*8 + i)*H_DIM + 4*c];
        acc[0][i] = fmaf(w0.x,hv.x,fmaf(w0.y,hv.y,fmaf(w0.z,hv.z,fmaf(w0.w,hv.w,acc[0][i]))));
        acc[1][i] = fmaf(w1.x,hv.x,fmaf(w1.y,hv.y,fmaf(w1.z,hv.z,fmaf(w1.w,hv.w,acc[1][i]))));
        acc[2][i] = fmaf(w2.x,hv.x,fmaf(w2.y,hv.y,fmaf(w2.z,hv.z,fmaf(w2.w,hv.w,acc[2][i]))));
        acc[3][i] = fmaf(w3.x,hv.x,fmaf(w3.y,hv.y,fmaf(w3.z,hv.z,fmaf(w3.w,hv.w,acc[3][i]))));
      }
    }

    // ---- combine k-quarters (lanes 4m..4m+3 hold same (u,bq)) ----
    #pragma unroll
    for (int j = 0; j < 4; ++j)
      #pragma unroll
      for (int i = 0; i < 8; ++i) {
        float v = acc[j][i];
        v += __shfl_xor(v, 1);
        v += __shfl_xor(v, 2);
        acc[j][i] = v;
      }

    __syncthreads();   // all h_s reads of step t complete

    // ---- gate activations + state update for 2 (b,u) pairs ----
    // batch index = kq*2 + q; select with compile-time indices (no runtime
    // array indexing -> no scratch).
    #pragma unroll
    for (int q = 0; q < 2; ++q) {
      float g0, g1, g2, g3;
      if (q == 0) {
        g0 = (kq==0)?acc[0][0]:(kq==1)?acc[0][2]:(kq==2)?acc[0][4]:acc[0][6];
        g1 = (kq==0)?acc[1][0]:(kq==1)?acc[1][2]:(kq==2)?acc[1][4]:acc[1][6];
        g2 = (kq==0)?acc[2][0]:(kq==1)?acc[2][2]:(kq==2)?acc[2][4]:acc[2][6];
        g3 = (kq==0)?acc[3][0]:(kq==1)?acc[3][2]:(kq==2)?acc[3][4]:acc[3][6];
      } else {
        g0 = (kq==0)?acc[0][1]:(kq==1)?acc[0][3]:(kq==2)?acc[0][5]:acc[0][7];
        g1 = (kq==0)?acc[1][1]:(kq==1)?acc[1][3]:(kq==2)?acc[1][5]:acc[1][7];
        g2 = (kq==0)?acc[2][1]:(kq==1)?acc[2][3]:(kq==2)?acc[2][5]:acc[2][7];
        g3 = (kq==0)?acc[3][1]:(kq==1)?acc[3][3]:(kq==2)?acc[3][5]:acc[3][7];
      }
      const int il = kq*2 + q;
      const int b  = bq*8 + il;
      const float gi = g0 + bias[0];
      const float gf = g1 + bias[1];
      const float gg = g2 + bias[2];
      const float go = g3 + bias[3];
      const float cprev = q ? cst1 : cst0;
      const float cn = sigm(gf)*cprev + sigm(gi)*tanh_fast(gg);
      if (q) cst1 = cn; else cst0 = cn;
      const float hn = sigm(go) * tanh_fast(cn);
      h_s[b*H_DIM + u] = hn;
      if constexpr (WRITE_H)
        h_out[((size_t)(b0 + b)*T_LEN + t)*H_DIM + u] = hn;
    }
    __syncthreads();   // new h visible before next step's reads
  }

  if constexpr (LAST_FC) {
    // out[b] = h_last[b] . wfc + bfc  (tiny; 16 lanes, once per kernel)
    if (tid < BB) {
      float s = bfc[0];
      #pragma unroll 4
      for (int uu = 0; uu < H_DIM; ++uu)
        s = fmaf(h_s[tid*H_DIM + uu], wfc[uu], s);
      out[b0 + tid] = s;
    }
  }
}

extern "C" void kernel_launch(void* const* d_in, const int* in_sizes, int n_in,
                              void* d_out, int out_size, void* d_ws, size_t ws_size,
                              hipStream_t stream) {
  (void)in_sizes; (void)n_in; (void)out_size; (void)ws_size;

  const float* x    = (const float*)d_in[0];
  const float* Wih0 = (const float*)d_in[1];
  const float* Whh0 = (const float*)d_in[2];
  const float* bih0 = (const float*)d_in[3];
  const float* bhh0 = (const float*)d_in[4];
  const float* Wih1 = (const float*)d_in[5];
  const float* Whh1 = (const float*)d_in[6];
  const float* bih1 = (const float*)d_in[7];
  const float* bhh1 = (const float*)d_in[8];
  const float* Wfc  = (const float*)d_in[9];
  const float* bfc  = (const float*)d_in[10];
  float* out = (float*)d_out;

  float* h1 = (float*)d_ws;   // (B,T,96) fp32 = 252 MiB

  // 153.6 KB dynamic LDS (> 64 KB default cap) — opt in every call (idempotent,
  // host-side, not stream-ordered; graph-capture safe).
  hipFuncSetAttribute((const void*)lstm_kernel<D_IN, true, false>,
                      hipFuncAttributeMaxDynamicSharedMemorySize, SMEM_BYTES);
  hipFuncSetAttribute((const void*)lstm_kernel<H_DIM, false, true>,
                      hipFuncAttributeMaxDynamicSharedMemorySize, SMEM_BYTES);

  dim3 grid(B_TOT / BB);   // 256 blocks -> 1 per CU
  dim3 block(NTHR);

  lstm_kernel<D_IN, true, false><<<grid, block, SMEM_BYTES, stream>>>(
      x, Wih0, Whh0, bih0, bhh0, h1, nullptr, nullptr, nullptr);

  lstm_kernel<H_DIM, false, true><<<grid, block, SMEM_BYTES, stream>>>(
      h1, Wih1, Whh1, bih1, bhh1, nullptr, Wfc, bfc, out);
}

// Round 3
// 2607.241 us; speedup vs baseline: 1.9653x; 1.9653x over previous
//
#include <hip/hip_runtime.h>
#include <cstddef>

// Problem constants
#define B_TOT 4096
#define T_LEN 168
#define D_IN  16
#define H_DIM 96
#define G_DIM 384   // 4*H

#define NTHR  768   // 12 waves: tid = u*8 + kq  (u 0..95, kq 0..7)
#define HP    104   // padded h row: read=broadcast-distinct, write=2-way (free)

__device__ __forceinline__ float sigm(float x) {
  return __fdividef(1.f, 1.f + __expf(-x));
}
__device__ __forceinline__ float tanh_fast(float x) {
  float ax = fabsf(x);
  float z  = __expf(-2.f * ax);
  float t  = __fdividef(1.f - z, 1.f + z);
  return copysignf(t, x);
}

// Persistent LSTM layer. Each block: 2 sequential tiles of 8 batches.
// Thread (u, kq): owns gate rows {u+96j}, k-slice [kq*12, kq*12+12) of Whh in
// 48 VGPRs; accumulates gate partials for all 8 batches (slot i <-> batch kq^i);
// retiring xor-butterfly (28 shfl) leaves slot0 = full sum for batch kq; thread
// then does the whole i/f/g/o -> (c,h) update for (b=kq, u). c stays in a VGPR.
// h tile double-buffered in LDS -> ONE barrier per step.
// Layer 0: whole x-tile (8x168x16 = 86 KB) staged in LDS once per tile.
// Layer 1: Wih staged in LDS once (rotation-swizzled, conflict-free reads);
//          x row (8x96) staged per step, double-buffered (issue-early/write-late).
template<int K_IN, bool WRITE_H, bool LAST_FC>
__global__ __launch_bounds__(NTHR)
void lstm_kernel(const float* __restrict__ in,     // (B,T,K_IN)
                 const float* __restrict__ wih,    // (384,K_IN)
                 const float* __restrict__ whh,    // (384,96)
                 const float* __restrict__ bih,    // (384)
                 const float* __restrict__ bhh,    // (384)
                 float* __restrict__ h_out,        // (B,T,96) layer0
                 const float* __restrict__ wfc,    // (96) layer1
                 const float* __restrict__ bfc,    // (1) layer1
                 float* __restrict__ out)          // (B,) layer1
{
  constexpr bool WLDS = (K_IN == 96);   // layer 1

  extern __shared__ float smem[];
  // layer1: [wih_s 36864][x2_s 2*768][h_s 2*8*HP]   = 160256 B
  // layer0: [x_s 8*168*16][h_s 2*8*HP]              =  92672 B
  float* wih_s = smem;
  float* x_s   = smem + (WLDS ? G_DIM * H_DIM : 0);
  float* h_s   = x_s + (WLDS ? 2 * NTHR : 8 * T_LEN * D_IN);

  const int tid = threadIdx.x;
  const int u   = tid >> 3;     // 0..95
  const int kq  = tid & 7;      // lane bits 0..2

  // ---- one-time staging: rotated Wih (layer 1) ----
  if constexpr (WLDS) {
    // float4 chunk (row g, ch) -> slot g*24 + (ch + g%24)%24.
    // Read addr mod 128B becomes 4*((3kq+c+u) mod 8): same-kq lanes (u+1 apart)
    // and same-u lanes (3kq distinct mod 8) both hit distinct bank-quads.
    for (int idx = tid; idx < G_DIM * 24; idx += NTHR) {
      int g  = idx / 24;
      int ch = idx - g * 24;
      int cr = ch + (g % 24); if (cr >= 24) cr -= 24;
      ((float4*)wih_s)[g * 24 + cr] = ((const float4*)wih)[idx];
    }
  }

  // Whh slice -> 48 VGPRs: rows u+96j, k in [kq*12, kq*12+12)
  float4 wB[4][3];
  #pragma unroll
  for (int j = 0; j < 4; ++j)
    #pragma unroll
    for (int c = 0; c < 3; ++c)
      wB[j][c] = *(const float4*)(whh + (size_t)(u + 96 * j) * 96 + kq * 12 + 4 * c);

  float2 wA0[4];                 // layer-0 Wih slice (8 VGPRs)
  if constexpr (!WLDS) {
    #pragma unroll
    for (int j = 0; j < 4; ++j)
      wA0[j] = *(const float2*)(wih + (u + 96 * j) * K_IN + kq * 2);
  }

  float bias[4];
  #pragma unroll
  for (int j = 0; j < 4; ++j) bias[j] = bih[u + 96 * j] + bhh[u + 96 * j];

  const int xb  = tid / 96;          // layer-1 x-staging: batch row 0..7
  const int xc  = tid - xb * 96;     //                    col 0..95
  const int rot = u % 24;            // wih_s rotation base

  for (int tile = 0; tile < 2; ++tile) {
    const int gb0 = blockIdx.x * 16 + tile * 8;

    if constexpr (!WLDS) {
      // stage whole x-tile: rows gb0..gb0+8 contiguous = 5376 float4
      const float4* s4 = (const float4*)(in + (size_t)gb0 * T_LEN * D_IN);
      #pragma unroll
      for (int r = 0; r < 7; ++r)
        ((float4*)x_s)[tid + r * NTHR] = s4[tid + r * NTHR];
    } else {
      // stage x[0] into xbuf0 (1 coalesced dword/thread)
      x_s[tid] = in[((size_t)(gb0 + xb) * T_LEN) * 96 + xc];
    }
    for (int idx = tid; idx < 8 * HP; idx += NTHR) h_s[idx] = 0.f;  // h0 = 0
    __syncthreads();

    const float* xin = WLDS ? (in + (size_t)(gb0 + xb) * T_LEN * 96 + xc) : nullptr;

    float cst = 0.f;

    #pragma unroll 1
    for (int t = 0; t < T_LEN; ++t) {
      const int rd = t & 1;
      const float* hr = h_s + rd * 8 * HP;
      float*       hw = h_s + (rd ^ 1) * 8 * HP;

      float acc[4][8];
      #pragma unroll
      for (int j = 0; j < 4; ++j)
        #pragma unroll
        for (int i = 0; i < 8; ++i) acc[j][i] = 0.f;

      // issue next-step x load early (layer 1); write to LDS late
      float xstage = 0.f;
      if constexpr (WLDS) {
        if (t + 1 < T_LEN) xstage = xin[(t + 1) * 96];
      }

      // ---- B-part: h @ Whh^T (hv from LDS, broadcast-distinct banks) ----
      #pragma unroll
      for (int c = 0; c < 3; ++c) {
        float4 hv[8];
        #pragma unroll
        for (int i = 0; i < 8; ++i)
          hv[i] = *(const float4*)&hr[(kq ^ i) * HP + kq * 12 + 4 * c];
        #pragma unroll
        for (int j = 0; j < 4; ++j)
          #pragma unroll
          for (int i = 0; i < 8; ++i)
            acc[j][i] = fmaf(wB[j][c].x, hv[i].x, fmaf(wB[j][c].y, hv[i].y,
                        fmaf(wB[j][c].z, hv[i].z, fmaf(wB[j][c].w, hv[i].w, acc[j][i]))));
      }

      if constexpr (!WLDS) {
        // ---- layer-0 A-part: x from LDS tile, weights in regs ----
        float2 xv2[8];
        #pragma unroll
        for (int i = 0; i < 8; ++i)
          xv2[i] = *(const float2*)&x_s[(kq ^ i) * (T_LEN * D_IN) + t * D_IN + kq * 2];
        #pragma unroll
        for (int j = 0; j < 4; ++j)
          #pragma unroll
          for (int i = 0; i < 8; ++i)
            acc[j][i] = fmaf(wA0[j].x, xv2[i].x, fmaf(wA0[j].y, xv2[i].y, acc[j][i]));
      } else {
        // ---- layer-1 A-part: wih from rotated LDS, x from xbuf[t&1] ----
        const float* xrow = x_s + rd * NTHR;
        #pragma unroll
        for (int c = 0; c < 3; ++c) {
          int cr = 3 * kq + c + rot; if (cr >= 24) cr -= 24;
          float4 wA[4];
          #pragma unroll
          for (int j = 0; j < 4; ++j)
            wA[j] = *(const float4*)&wih_s[(u + 96 * j) * 96 + 4 * cr];
          float4 xv[8];
          #pragma unroll
          for (int i = 0; i < 8; ++i)
            xv[i] = *(const float4*)&xrow[(kq ^ i) * 96 + kq * 12 + 4 * c];
          #pragma unroll
          for (int j = 0; j < 4; ++j)
            #pragma unroll
            for (int i = 0; i < 8; ++i)
              acc[j][i] = fmaf(wA[j].x, xv[i].x, fmaf(wA[j].y, xv[i].y,
                          fmaf(wA[j].z, xv[i].z, fmaf(wA[j].w, xv[i].w, acc[j][i]))));
        }
      }

      // ---- retiring xor-butterfly over the 8 kq lanes ----
      // slot i holds batch kq^i; after 3 rounds slot0 = full sum for b=kq.
      #pragma unroll
      for (int j = 0; j < 4; ++j) {
        #pragma unroll
        for (int i = 0; i < 4; ++i) acc[j][i] += __shfl_xor(acc[j][i ^ 4], 4);
        #pragma unroll
        for (int i = 0; i < 2; ++i) acc[j][i] += __shfl_xor(acc[j][i ^ 2], 2);
        acc[j][0] += __shfl_xor(acc[j][1], 1);
      }

      // ---- gates + state update (b = kq, unit u) ----
      const float gi = acc[0][0] + bias[0];
      const float gf = acc[1][0] + bias[1];
      const float gg = acc[2][0] + bias[2];
      const float go = acc[3][0] + bias[3];
      cst = sigm(gf) * cst + sigm(gi) * tanh_fast(gg);
      const float hn = sigm(go) * tanh_fast(cst);
      hw[kq * HP + u] = hn;
      if constexpr (WRITE_H)
        h_out[((size_t)(gb0 + kq) * T_LEN + t) * H_DIM + u] = hn;

      if constexpr (WLDS) {
        if (t + 1 < T_LEN) x_s[(rd ^ 1) * NTHR + tid] = xstage;  // write-late
      }

      __syncthreads();   // one barrier per step
    }

    if constexpr (LAST_FC) {
      // last h is in buf0 (T=168 even)
      if (tid < 8) {
        const float* hl = h_s + tid * HP;
        float s = bfc[0];
        #pragma unroll 4
        for (int uu = 0; uu < H_DIM; ++uu) s = fmaf(hl[uu], wfc[uu], s);
        out[gb0 + tid] = s;
      }
    }
    __syncthreads();   // protect h_s/x_s before next tile's restaging
  }
}

extern "C" void kernel_launch(void* const* d_in, const int* in_sizes, int n_in,
                              void* d_out, int out_size, void* d_ws, size_t ws_size,
                              hipStream_t stream) {
  (void)in_sizes; (void)n_in; (void)out_size; (void)ws_size;

  const float* x    = (const float*)d_in[0];
  const float* Wih0 = (const float*)d_in[1];
  const float* Whh0 = (const float*)d_in[2];
  const float* bih0 = (const float*)d_in[3];
  const float* bhh0 = (const float*)d_in[4];
  const float* Wih1 = (const float*)d_in[5];
  const float* Whh1 = (const float*)d_in[6];
  const float* bih1 = (const float*)d_in[7];
  const float* bhh1 = (const float*)d_in[8];
  const float* Wfc  = (const float*)d_in[9];
  const float* bfc  = (const float*)d_in[10];
  float* out = (float*)d_out;

  float* h1 = (float*)d_ws;   // (B,T,96) fp32 = 252 MiB

  constexpr int SMEM0 = (8 * T_LEN * D_IN + 2 * 8 * HP) * 4;          //  92672 B
  constexpr int SMEM1 = (G_DIM * H_DIM + 2 * NTHR + 2 * 8 * HP) * 4;  // 160256 B

  hipFuncSetAttribute((const void*)lstm_kernel<D_IN, true, false>,
                      hipFuncAttributeMaxDynamicSharedMemorySize, SMEM0);
  hipFuncSetAttribute((const void*)lstm_kernel<H_DIM, false, true>,
                      hipFuncAttributeMaxDynamicSharedMemorySize, SMEM1);

  dim3 grid(B_TOT / 16);   // 256 blocks, 1/CU; each does 2 tiles of 8 batches
  dim3 block(NTHR);

  lstm_kernel<D_IN, true, false><<<grid, block, SMEM0, stream>>>(
      x, Wih0, Whh0, bih0, bhh0, h1, nullptr, nullptr, nullptr);

  lstm_kernel<H_DIM, false, true><<<grid, block, SMEM1, stream>>>(
      h1, Wih1, Whh1, bih1, bhh1, nullptr, Wfc, bfc, out);
}

// Round 4
// 2319.820 us; speedup vs baseline: 2.2088x; 1.1239x over previous
//
#include <hip/hip_runtime.h>
#include <cstddef>

// Problem constants
#define B_TOT 4096
#define T_LEN 168
#define D_IN  16
#define H_DIM 96

#define NTHR 768   // 12 waves; tid = u*8 + kq (u 0..95, kq 0..7)
#define HP   104   // layer-0 padded h row
#define VP   196   // layer-1 combined [x|h] row: 196 ≡ 16 mod 128B -> bijective banks

__device__ __forceinline__ float sigm(float x) {
  return __fdividef(1.f, 1.f + __expf(-x));
}
__device__ __forceinline__ float tanh_fast(float x) {
  float ax = fabsf(x);
  float z  = __expf(-2.f * ax);
  return copysignf(__fdividef(1.f - z, 1.f + z), x);
}

// ---------------- Layer 0 ----------------
// Round-3 structure (x-tile in LDS, Whh slice + Wih slice in regs) with
// __launch_bounds__(768,3): 170-VGPR budget so the 56 weight VGPRs stay live.
__global__ __launch_bounds__(NTHR, 3)
void lstm0_kernel(const float* __restrict__ in,    // (B,T,16)
                  const float* __restrict__ wih,   // (384,16)
                  const float* __restrict__ whh,   // (384,96)
                  const float* __restrict__ bih,
                  const float* __restrict__ bhh,
                  float* __restrict__ h_out)       // (B,T,96)
{
  extern __shared__ float smem[];
  float* x_s = smem;                       // [8][168*16] = 86016 B
  float* h_s = smem + 8 * T_LEN * D_IN;    // [2][8][HP]  =  6656 B

  const int tid = threadIdx.x;
  const int u   = tid >> 3;
  const int kq  = tid & 7;

  float4 wB[4][3];   // Whh rows u+96j, k-slice [12kq,12kq+12)
  #pragma unroll
  for (int j = 0; j < 4; ++j)
    #pragma unroll
    for (int c = 0; c < 3; ++c)
      wB[j][c] = *(const float4*)(whh + (size_t)(u + 96 * j) * 96 + kq * 12 + 4 * c);

  float2 wA0[4];     // Wih rows u+96j, k-slice [2kq,2kq+2)
  #pragma unroll
  for (int j = 0; j < 4; ++j)
    wA0[j] = *(const float2*)(wih + (u + 96 * j) * D_IN + kq * 2);

  float bias[4];
  #pragma unroll
  for (int j = 0; j < 4; ++j) bias[j] = bih[u + 96 * j] + bhh[u + 96 * j];

  for (int tile = 0; tile < 2; ++tile) {
    const int gb0 = blockIdx.x * 16 + tile * 8;

    // stage x tile (8 rows contiguous = 5376 float4) + zero h buf0
    {
      const float4* s4 = (const float4*)(in + (size_t)gb0 * T_LEN * D_IN);
      #pragma unroll
      for (int r = 0; r < 7; ++r)
        ((float4*)x_s)[tid + r * NTHR] = s4[tid + r * NTHR];
    }
    for (int idx = tid; idx < 8 * HP; idx += NTHR) h_s[idx] = 0.f;
    __syncthreads();

    float cst = 0.f;

    #pragma unroll 2
    for (int t = 0; t < T_LEN; ++t) {
      const int rd = t & 1;
      const float* hr = h_s + rd * 8 * HP;
      float*       hw = h_s + (rd ^ 1) * 8 * HP;

      float acc[4][8];
      #pragma unroll
      for (int j = 0; j < 4; ++j)
        #pragma unroll
        for (int i = 0; i < 8; ++i) acc[j][i] = 0.f;

      // B-part: h @ Whh^T (conflict-free: 8 distinct quads, broadcast over u)
      #pragma unroll
      for (int c = 0; c < 3; ++c) {
        float4 hv[8];
        #pragma unroll
        for (int i = 0; i < 8; ++i)
          hv[i] = *(const float4*)&hr[(kq ^ i) * HP + kq * 12 + 4 * c];
        #pragma unroll
        for (int j = 0; j < 4; ++j)
          #pragma unroll
          for (int i = 0; i < 8; ++i)
            acc[j][i] = fmaf(wB[j][c].x, hv[i].x, fmaf(wB[j][c].y, hv[i].y,
                        fmaf(wB[j][c].z, hv[i].z, fmaf(wB[j][c].w, hv[i].w, acc[j][i]))));
      }

      // A-part: x from LDS tile, weights in regs
      {
        float2 xv2[8];
        #pragma unroll
        for (int i = 0; i < 8; ++i)
          xv2[i] = *(const float2*)&x_s[(kq ^ i) * (T_LEN * D_IN) + t * D_IN + kq * 2];
        #pragma unroll
        for (int j = 0; j < 4; ++j)
          #pragma unroll
          for (int i = 0; i < 8; ++i)
            acc[j][i] = fmaf(wA0[j].x, xv2[i].x, fmaf(wA0[j].y, xv2[i].y, acc[j][i]));
      }

      // retiring xor-butterfly: slot0 <- full sum for batch kq
      #pragma unroll
      for (int j = 0; j < 4; ++j) {
        #pragma unroll
        for (int i = 0; i < 4; ++i) acc[j][i] += __shfl_xor(acc[j][i ^ 4], 4);
        #pragma unroll
        for (int i = 0; i < 2; ++i) acc[j][i] += __shfl_xor(acc[j][i ^ 2], 2);
        acc[j][0] += __shfl_xor(acc[j][1], 1);
      }

      const float gi = acc[0][0] + bias[0];
      const float gf = acc[1][0] + bias[1];
      const float gg = acc[2][0] + bias[2];
      const float go = acc[3][0] + bias[3];
      cst = sigm(gf) * cst + sigm(gi) * tanh_fast(gg);
      const float hn = sigm(go) * tanh_fast(cst);
      hw[kq * HP + u] = hn;
      h_out[((size_t)(gb0 + kq) * T_LEN + t) * H_DIM + u] = hn;

      __syncthreads();
    }
    // final sync of the loop protects x_s/h_s restaging for the next tile
  }
}

// ---------------- Layer 1 ----------------
// Combined-K GEMM: W = [Wih1 | Whh1] (384x192) fully register-resident
// (96 VGPR/thread); per-step vector concat[x_t; h_t] double-buffered in a
// tiny LDS buffer [2][8][VP].  No per-step weight reads at all.
__global__ __launch_bounds__(NTHR, 3)
void lstm1_kernel(const float* __restrict__ in,    // (B,T,96) = h1 from layer0
                  const float* __restrict__ wih,   // (384,96)
                  const float* __restrict__ whh,   // (384,96)
                  const float* __restrict__ bih,
                  const float* __restrict__ bhh,
                  const float* __restrict__ wfc,   // (96)
                  const float* __restrict__ bfc,   // (1)
                  float* __restrict__ out)         // (B,)
{
  __shared__ float cb[2][8][VP];   // 12544 B: [0..96)=x_t, [96..192)=h_t

  const int tid = threadIdx.x;
  const int u   = tid >> 3;
  const int kq  = tid & 7;

  // combined weight slice: rows u+96j, k in [24kq, 24kq+24) of [Wih|Whh]
  float4 w[4][6];
  #pragma unroll
  for (int j = 0; j < 4; ++j) {
    const size_t row = (size_t)(u + 96 * j) * 96;
    const float* wsrc = (kq < 4) ? (wih + row + kq * 24) : (whh + row + (kq - 4) * 24);
    #pragma unroll
    for (int c = 0; c < 6; ++c) w[j][c] = *(const float4*)(wsrc + 4 * c);
  }

  float bias[4];
  #pragma unroll
  for (int j = 0; j < 4; ++j) bias[j] = bih[u + 96 * j] + bhh[u + 96 * j];

  const int xb = tid / 96;          // x-staging: batch row 0..7
  const int xc = tid - xb * 96;     //            col 0..95

  for (int tile = 0; tile < 2; ++tile) {
    const int gb0 = blockIdx.x * 16 + tile * 8;
    const float* xin = in + (size_t)(gb0 + xb) * T_LEN * 96 + xc;

    cb[0][kq][96 + u] = 0.f;        // h0 = 0 (768 writes cover 8x96 exactly)
    cb[0][xb][xc]     = xin[0];     // x_0
    __syncthreads();

    float cst = 0.f;

    #pragma unroll 2
    for (int t = 0; t < T_LEN; ++t) {
      const int rd = t & 1;
      const float* v  = &cb[rd][0][0];
      float*       vw = &cb[rd ^ 1][0][0];

      float xstage = 0.f;
      if (t + 1 < T_LEN) xstage = xin[(size_t)(t + 1) * 96];   // issue early

      float acc[4][8];
      #pragma unroll
      for (int j = 0; j < 4; ++j)
        #pragma unroll
        for (int i = 0; i < 8; ++i) acc[j][i] = 0.f;

      // K=192 in 6 float4 chunks; hv in two groups of 4 to cap liveness
      #pragma unroll
      for (int c = 0; c < 6; ++c) {
        {
          float4 hv[4];
          #pragma unroll
          for (int i = 0; i < 4; ++i)
            hv[i] = *(const float4*)&v[(kq ^ i) * VP + kq * 24 + 4 * c];
          #pragma unroll
          for (int j = 0; j < 4; ++j)
            #pragma unroll
            for (int i = 0; i < 4; ++i)
              acc[j][i] = fmaf(w[j][c].x, hv[i].x, fmaf(w[j][c].y, hv[i].y,
                          fmaf(w[j][c].z, hv[i].z, fmaf(w[j][c].w, hv[i].w, acc[j][i]))));
        }
        {
          float4 hv[4];
          #pragma unroll
          for (int i = 0; i < 4; ++i)
            hv[i] = *(const float4*)&v[(kq ^ (i + 4)) * VP + kq * 24 + 4 * c];
          #pragma unroll
          for (int j = 0; j < 4; ++j)
            #pragma unroll
            for (int i = 0; i < 4; ++i)
              acc[j][i + 4] = fmaf(w[j][c].x, hv[i].x, fmaf(w[j][c].y, hv[i].y,
                              fmaf(w[j][c].z, hv[i].z, fmaf(w[j][c].w, hv[i].w, acc[j][i + 4]))));
        }
      }

      // retiring xor-butterfly: slot0 <- full sum for batch kq
      #pragma unroll
      for (int j = 0; j < 4; ++j) {
        #pragma unroll
        for (int i = 0; i < 4; ++i) acc[j][i] += __shfl_xor(acc[j][i ^ 4], 4);
        #pragma unroll
        for (int i = 0; i < 2; ++i) acc[j][i] += __shfl_xor(acc[j][i ^ 2], 2);
        acc[j][0] += __shfl_xor(acc[j][1], 1);
      }

      const float gi = acc[0][0] + bias[0];
      const float gf = acc[1][0] + bias[1];
      const float gg = acc[2][0] + bias[2];
      const float go = acc[3][0] + bias[3];
      cst = sigm(gf) * cst + sigm(gi) * tanh_fast(gg);
      const float hn = sigm(go) * tanh_fast(cst);

      vw[kq * VP + 96 + u] = hn;                      // h_{t+1}
      if (t + 1 < T_LEN) vw[xb * VP + xc] = xstage;   // x_{t+1} (write late)

      __syncthreads();
    }

    // fused FC on last h (in cb[0]: T=168 even)
    if (tid < 8) {
      float s = bfc[0];
      const float* hl = &cb[0][tid][96];
      #pragma unroll 4
      for (int uu = 0; uu < H_DIM; ++uu) s = fmaf(hl[uu], wfc[uu], s);
      out[gb0 + tid] = s;
    }
    __syncthreads();   // protect cb before next tile's restage
  }
}

extern "C" void kernel_launch(void* const* d_in, const int* in_sizes, int n_in,
                              void* d_out, int out_size, void* d_ws, size_t ws_size,
                              hipStream_t stream) {
  (void)in_sizes; (void)n_in; (void)out_size; (void)ws_size;

  const float* x    = (const float*)d_in[0];
  const float* Wih0 = (const float*)d_in[1];
  const float* Whh0 = (const float*)d_in[2];
  const float* bih0 = (const float*)d_in[3];
  const float* bhh0 = (const float*)d_in[4];
  const float* Wih1 = (const float*)d_in[5];
  const float* Whh1 = (const float*)d_in[6];
  const float* bih1 = (const float*)d_in[7];
  const float* bhh1 = (const float*)d_in[8];
  const float* Wfc  = (const float*)d_in[9];
  const float* bfc  = (const float*)d_in[10];
  float* out = (float*)d_out;

  float* h1 = (float*)d_ws;   // (B,T,96) fp32 = 252 MiB

  constexpr int SMEM0 = (8 * T_LEN * D_IN + 2 * 8 * HP) * 4;   // 92672 B

  hipFuncSetAttribute((const void*)lstm0_kernel,
                      hipFuncAttributeMaxDynamicSharedMemorySize, SMEM0);

  dim3 grid(B_TOT / 16);   // 256 blocks; each does 2 tiles of 8 batches
  dim3 block(NTHR);

  lstm0_kernel<<<grid, block, SMEM0, stream>>>(x, Wih0, Whh0, bih0, bhh0, h1);
  lstm1_kernel<<<grid, block, 0, stream>>>(h1, Wih1, Whh1, bih1, bhh1, Wfc, bfc, out);
}

// Round 6
// 2155.480 us; speedup vs baseline: 2.3772x; 1.0762x over previous
//
#include <hip/hip_runtime.h>
#include <cstddef>

// Problem constants
#define B_TOT 4096
#define T_LEN 168
#define D_IN  16
#define H_DIM 96

#define NTHR 768   // 12 waves; tid = u*8 + kq (u 0..95, kq 0..7)
#define HP   104   // layer-0 padded h row (bank-verified, conflicts=0 measured)
#define VP   196   // layer-1 combined [x|h] row (bank-verified, conflicts=0 measured)

__device__ __forceinline__ float sigm(float x) {
  return __fdividef(1.f, 1.f + __expf(-x));
}
__device__ __forceinline__ float tanh_fast(float x) {
  float ax = fabsf(x);
  float z  = __expf(-2.f * ax);
  return copysignf(__fdividef(1.f - z, 1.f + z), x);
}

// DPP cross-lane move (VALU pipe — keeps the reduction off the DS pipe).
// CTRL: 0xB1 = quad_perm [1,0,3,2] (xor-1), 0x4E = quad_perm [2,3,0,1] (xor-2),
//       0x141 = row_half_mirror (xor-7 within octet).
// Masks {7,2,1} generate the full 8-group over kq = lane&7.
template<int CTRL>
__device__ __forceinline__ float dppmov(float x) {
  return __builtin_bit_cast(float,
      __builtin_amdgcn_update_dpp(0, __builtin_bit_cast(int, x),
                                  CTRL, 0xF, 0xF, true));
}

// Retiring DPP butterfly: slot i of lane l holds batch l^i partial; after the
// three rounds slot0 = full K-sum for batch l.  (Round m pairs slot i with i^m
// from lane l^m: batch (l^m)^(i^m) = l^i, so batches stay aligned.)
#define BUTTERFLY(accj)                         \
  do {                                          \
    accj[0] += dppmov<0x141>(accj[7]);          \
    accj[1] += dppmov<0x141>(accj[6]);          \
    accj[2] += dppmov<0x141>(accj[5]);          \
    accj[3] += dppmov<0x141>(accj[4]);          \
    accj[0] += dppmov<0x4E>(accj[2]);           \
    accj[1] += dppmov<0x4E>(accj[3]);           \
    accj[0] += dppmov<0xB1>(accj[1]);           \
  } while (0)

// Pin a value into a VGPR as a non-rematerializable asm result: the register
// allocator must keep it live (it cannot re-load it from memory).  This is
// what actually makes the weights register-resident — __launch_bounds__ alone
// left them reloaded every step (VGPR_Count=84 observed, round 4).
#define PINF(x) asm volatile("" : "+v"(x))
__device__ __forceinline__ void pin4(float4& v) { PINF(v.x); PINF(v.y); PINF(v.z); PINF(v.w); }
__device__ __forceinline__ void pin2(float2& v) { PINF(v.x); PINF(v.y); }

// ---------------- Layer 0 ----------------
__global__ __launch_bounds__(NTHR, 3)
void lstm0_kernel(const float* __restrict__ in,    // (B,T,16)
                  const float* __restrict__ wih,   // (384,16)
                  const float* __restrict__ whh,   // (384,96)
                  const float* __restrict__ bih,
                  const float* __restrict__ bhh,
                  float* __restrict__ h_out)       // (B,T,96)
{
  extern __shared__ float smem[];
  float* x_s = smem;                       // [8][168*16] = 86016 B
  float* h_s = smem + 8 * T_LEN * D_IN;    // [2][8][HP]  =  6656 B

  const int tid = threadIdx.x;
  const int u   = tid >> 3;
  const int kq  = tid & 7;

  float4 wB[4][3];   // Whh rows u+96j, k-slice [12kq,12kq+12)
  #pragma unroll
  for (int j = 0; j < 4; ++j)
    #pragma unroll
    for (int c = 0; c < 3; ++c) {
      wB[j][c] = *(const float4*)(whh + (size_t)(u + 96 * j) * 96 + kq * 12 + 4 * c);
      pin4(wB[j][c]);
    }

  float2 wA0[4];     // Wih rows u+96j, k-slice [2kq,2kq+2)
  #pragma unroll
  for (int j = 0; j < 4; ++j) {
    wA0[j] = *(const float2*)(wih + (u + 96 * j) * D_IN + kq * 2);
    pin2(wA0[j]);
  }

  float bias[4];
  #pragma unroll
  for (int j = 0; j < 4; ++j) {
    bias[j] = bih[u + 96 * j] + bhh[u + 96 * j];
    PINF(bias[j]);
  }

  for (int tile = 0; tile < 2; ++tile) {
    const int gb0 = blockIdx.x * 16 + tile * 8;

    {
      const float4* s4 = (const float4*)(in + (size_t)gb0 * T_LEN * D_IN);
      #pragma unroll
      for (int r = 0; r < 7; ++r)
        ((float4*)x_s)[tid + r * NTHR] = s4[tid + r * NTHR];
    }
    for (int idx = tid; idx < 8 * HP; idx += NTHR) h_s[idx] = 0.f;
    __syncthreads();

    float cst = 0.f;

    #pragma unroll 1
    for (int t = 0; t < T_LEN; ++t) {
      const int rd = t & 1;
      const float* hr = h_s + rd * 8 * HP;
      float*       hw = h_s + (rd ^ 1) * 8 * HP;

      float acc[4][8];
      #pragma unroll
      for (int j = 0; j < 4; ++j)
        #pragma unroll
        for (int i = 0; i < 8; ++i) acc[j][i] = 0.f;

      // B-part: h @ Whh^T (bank-verified conflict-free)
      #pragma unroll
      for (int c = 0; c < 3; ++c) {
        float4 hv[8];
        #pragma unroll
        for (int i = 0; i < 8; ++i)
          hv[i] = *(const float4*)&hr[(kq ^ i) * HP + kq * 12 + 4 * c];
        #pragma unroll
        for (int j = 0; j < 4; ++j)
          #pragma unroll
          for (int i = 0; i < 8; ++i)
            acc[j][i] = fmaf(wB[j][c].x, hv[i].x, fmaf(wB[j][c].y, hv[i].y,
                        fmaf(wB[j][c].z, hv[i].z, fmaf(wB[j][c].w, hv[i].w, acc[j][i]))));
      }

      // A-part: x from LDS tile
      {
        float2 xv2[8];
        #pragma unroll
        for (int i = 0; i < 8; ++i)
          xv2[i] = *(const float2*)&x_s[(kq ^ i) * (T_LEN * D_IN) + t * D_IN + kq * 2];
        #pragma unroll
        for (int j = 0; j < 4; ++j)
          #pragma unroll
          for (int i = 0; i < 8; ++i)
            acc[j][i] = fmaf(wA0[j].x, xv2[i].x, fmaf(wA0[j].y, xv2[i].y, acc[j][i]));
      }

      #pragma unroll
      for (int j = 0; j < 4; ++j) BUTTERFLY(acc[j]);

      const float gi = acc[0][0] + bias[0];
      const float gf = acc[1][0] + bias[1];
      const float gg = acc[2][0] + bias[2];
      const float go = acc[3][0] + bias[3];
      cst = sigm(gf) * cst + sigm(gi) * tanh_fast(gg);
      const float hn = sigm(go) * tanh_fast(cst);
      hw[kq * HP + u] = hn;
      h_out[((size_t)(gb0 + kq) * T_LEN + t) * H_DIM + u] = hn;

      __syncthreads();
    }
  }
}

// ---------------- Layer 1 ----------------
// Combined-K GEMM: W = [Wih1 | Whh1] (384x192) register-resident (96 VGPR,
// asm-pinned); per-step concat[x_t; h_t] double-buffered in 12.5 KB LDS.
__global__ __launch_bounds__(NTHR, 3)
void lstm1_kernel(const float* __restrict__ in,    // (B,T,96) = h1
                  const float* __restrict__ wih,   // (384,96)
                  const float* __restrict__ whh,   // (384,96)
                  const float* __restrict__ bih,
                  const float* __restrict__ bhh,
                  const float* __restrict__ wfc,   // (96)
                  const float* __restrict__ bfc,   // (1)
                  float* __restrict__ out)         // (B,)
{
  __shared__ float cb[2][8][VP];   // [0..96)=x_t, [96..192)=h_t

  const int tid = threadIdx.x;
  const int u   = tid >> 3;
  const int kq  = tid & 7;

  // combined weight slice: rows u+96j, k in [24kq, 24kq+24) of [Wih|Whh]
  float4 w[4][6];
  #pragma unroll
  for (int j = 0; j < 4; ++j) {
    const size_t row = (size_t)(u + 96 * j) * 96;
    const float* wsrc = (kq < 4) ? (wih + row + kq * 24) : (whh + row + (kq - 4) * 24);
    #pragma unroll
    for (int c = 0; c < 6; ++c) {
      w[j][c] = *(const float4*)(wsrc + 4 * c);
      pin4(w[j][c]);
    }
  }

  float bias[4];
  #pragma unroll
  for (int j = 0; j < 4; ++j) {
    bias[j] = bih[u + 96 * j] + bhh[u + 96 * j];
    PINF(bias[j]);
  }

  const int xb = tid / 96;          // x-staging: batch row 0..7
  const int xc = tid - xb * 96;     //            col 0..95

  for (int tile = 0; tile < 2; ++tile) {
    const int gb0 = blockIdx.x * 16 + tile * 8;
    const float* xin = in + (size_t)(gb0 + xb) * T_LEN * 96 + xc;

    cb[0][kq][96 + u] = 0.f;        // h0 = 0
    cb[0][xb][xc]     = xin[0];     // x_0
    __syncthreads();

    float cst = 0.f;

    #pragma unroll 1
    for (int t = 0; t < T_LEN; ++t) {
      const int rd = t & 1;
      const float* v  = &cb[rd][0][0];
      float*       vw = &cb[rd ^ 1][0][0];

      float xstage = 0.f;
      if (t + 1 < T_LEN) xstage = xin[(size_t)(t + 1) * 96];   // issue early

      float acc[4][8];
      #pragma unroll
      for (int j = 0; j < 4; ++j)
        #pragma unroll
        for (int i = 0; i < 8; ++i) acc[j][i] = 0.f;

      // K=192 in 6 float4 chunks; hv in two groups of 4 (bank-verified)
      #pragma unroll
      for (int c = 0; c < 6; ++c) {
        {
          float4 hv[4];
          #pragma unroll
          for (int i = 0; i < 4; ++i)
            hv[i] = *(const float4*)&v[(kq ^ i) * VP + kq * 24 + 4 * c];
          #pragma unroll
          for (int j = 0; j < 4; ++j)
            #pragma unroll
            for (int i = 0; i < 4; ++i)
              acc[j][i] = fmaf(w[j][c].x, hv[i].x, fmaf(w[j][c].y, hv[i].y,
                          fmaf(w[j][c].z, hv[i].z, fmaf(w[j][c].w, hv[i].w, acc[j][i]))));
        }
        {
          float4 hv[4];
          #pragma unroll
          for (int i = 0; i < 4; ++i)
            hv[i] = *(const float4*)&v[(kq ^ (i + 4)) * VP + kq * 24 + 4 * c];
          #pragma unroll
          for (int j = 0; j < 4; ++j)
            #pragma unroll
            for (int i = 0; i < 4; ++i)
              acc[j][i + 4] = fmaf(w[j][c].x, hv[i].x, fmaf(w[j][c].y, hv[i].y,
                              fmaf(w[j][c].z, hv[i].z, fmaf(w[j][c].w, hv[i].w, acc[j][i + 4]))));
        }
      }

      #pragma unroll
      for (int j = 0; j < 4; ++j) BUTTERFLY(acc[j]);

      const float gi = acc[0][0] + bias[0];
      const float gf = acc[1][0] + bias[1];
      const float gg = acc[2][0] + bias[2];
      const float go = acc[3][0] + bias[3];
      cst = sigm(gf) * cst + sigm(gi) * tanh_fast(gg);
      const float hn = sigm(go) * tanh_fast(cst);

      vw[kq * VP + 96 + u] = hn;                      // h_{t+1}
      if (t + 1 < T_LEN) vw[xb * VP + xc] = xstage;   // x_{t+1} (write late)

      __syncthreads();
    }

    // fused FC on last h (in cb[0]: T=168 even)
    if (tid < 8) {
      float s = bfc[0];
      const float* hl = &cb[0][tid][96];
      #pragma unroll 4
      for (int uu = 0; uu < H_DIM; ++uu) s = fmaf(hl[uu], wfc[uu], s);
      out[gb0 + tid] = s;
    }
    __syncthreads();   // protect cb before next tile's restage
  }
}

extern "C" void kernel_launch(void* const* d_in, const int* in_sizes, int n_in,
                              void* d_out, int out_size, void* d_ws, size_t ws_size,
                              hipStream_t stream) {
  (void)in_sizes; (void)n_in; (void)out_size; (void)ws_size;

  const float* x    = (const float*)d_in[0];
  const float* Wih0 = (const float*)d_in[1];
  const float* Whh0 = (const float*)d_in[2];
  const float* bih0 = (const float*)d_in[3];
  const float* bhh0 = (const float*)d_in[4];
  const float* Wih1 = (const float*)d_in[5];
  const float* Whh1 = (const float*)d_in[6];
  const float* bih1 = (const float*)d_in[7];
  const float* bhh1 = (const float*)d_in[8];
  const float* Wfc  = (const float*)d_in[9];
  const float* bfc  = (const float*)d_in[10];
  float* out = (float*)d_out;

  float* h1 = (float*)d_ws;   // (B,T,96) fp32

  constexpr int SMEM0 = (8 * T_LEN * D_IN + 2 * 8 * HP) * 4;   // 92672 B

  hipFuncSetAttribute((const void*)lstm0_kernel,
                      hipFuncAttributeMaxDynamicSharedMemorySize, SMEM0);

  dim3 grid(B_TOT / 16);   // 256 blocks; each does 2 tiles of 8 batches
  dim3 block(NTHR);

  lstm0_kernel<<<grid, block, SMEM0, stream>>>(x, Wih0, Whh0, bih0, bhh0, h1);
  lstm1_kernel<<<grid, block, 0, stream>>>(h1, Wih1, Whh1, bih1, bhh1, Wfc, bfc, out);
}